// Round 8
// baseline (387.630 us; speedup 1.0000x reference)
//
#include <hip/hip_runtime.h>

#define N_SAMP   1024
#define IN_F     512
#define OUT_F    512
#define N_HEADS  32
#define N_SPLITS 4
#define DELTA_SCALE 0.1f

__device__ __forceinline__ void fma4(float4& a, float x, const float4& w) {
    a.x += x * w.x; a.y += x * w.y; a.z += x * w.z; a.w += x * w.w;
}
__device__ __forceinline__ void add4(float4& a, const float4& b) {
    a.x += b.x; a.y += b.y; a.z += b.z; a.w += b.w;
}

// role_pass<J, JG, KQ, KC, DELTA>, 128-col tile.
// threads = (ct = col-quad 0..31, kq = k-split 0..KQ-1, jg = sample-group).
// R7 spilled (VGPR cap 128, 210 MB scratch writes): base acc[32]x4 = 128 regs.
// Fix: split samples across waves (jg) instead of piling them per thread:
//   base  J=64 (one chunk covers max head -> W read ONCE), JT=16, acc=64 reg
//   delta J=16, JT=8, acc=32 reg
// W/D stream HBM->registers, dist-1 double-buffer with alternating indices
// (no rotation copies). X staged in KC-chunks (buf 64 KB); k-partials reduced
// via Red[KQ][J][32]f4 aliasing buf; sole-owner stores (no atomics). DELTA
// writes raw partials to ws so base/delta run concurrently in one dispatch.
template <int J, int JG, int KQ, int KC, bool DELTA>
__device__ __forceinline__ void role_pass(
    const float* __restrict__ X, const int* __restrict__ head_ix,
    const int* __restrict__ split_ix, const float* __restrict__ Wt,
    const float* __restrict__ bias, float* __restrict__ dst,
    int g, int tileIdx, float* buf, int* list, int* wsum)
{
    constexpr int JT   = J / JG;        // samples per thread
    constexpr int KTC  = KC / KQ;       // k-rows per thread per chunk
    constexpr int NSTC = KTC / 4;       // 4-row steps per chunk
    constexpr int NCH  = IN_F / KC;     // staged chunks

    const int tid  = threadIdx.x;
    const int lane = tid & 63, wave = tid >> 6;
    const int ct   = tid & 31;
    const int kq   = (tid >> 5) & (KQ - 1);
    const int jg   = tid / (32 * KQ);
    const int c0   = tileIdx * 128;

    // deterministic order-preserving compaction (all blocks of g agree)
    int run = 0;
    for (int r = 0; r < N_SAMP / 256; ++r) {
        const int i   = r * 256 + tid;
        const int key = DELTA ? head_ix[i] * N_SPLITS + split_ix[i] : head_ix[i];
        const bool hit = (key == g);
        const unsigned long long m = __ballot(hit);
        if (lane == 0) wsum[wave] = __popcll(m);
        __syncthreads();
        int base = run;
        for (int w = 0; w < 4; ++w)
            if (w < wave) base += wsum[w];
        if (hit)
            list[base + __popcll(m & ((1ULL << lane) - 1ULL))] = i;
        run += wsum[0] + wsum[1] + wsum[2] + wsum[3];
        __syncthreads();
    }
    const int total = run;
    if (total == 0) return;             // block-uniform

    const float* Wg = Wt + (size_t)g * (IN_F * OUT_F) + c0 + ct * 4;

    for (int s0 = 0; s0 < total; s0 += J) {   // expected 1 iteration
        const int nc = min(total - s0, J);

        float4 acc[JT];
#pragma unroll
        for (int j = 0; j < JT; ++j) acc[j] = make_float4(0.f, 0.f, 0.f, 0.f);

        for (int ch = 0; ch < NCH; ++ch) {
            const int kc = ch * KC;
            __syncthreads();            // buf may hold prev Red / prev chunk
            for (int i = tid; i < J * (KC / 4); i += 256) {
                const int s = i / (KC / 4), q = i % (KC / 4);
                float4 v = make_float4(0.f, 0.f, 0.f, 0.f);
                if (s < nc)
                    v = *(const float4*)(X + (size_t)list[s0 + s] * IN_F + kc + q * 4);
                *(float4*)(&buf[s * KC + q * 4]) = v;
            }
            __syncthreads();

            const float* wp = Wg + (size_t)(kc + kq * KTC) * OUT_F;
            float4 rb[2][4];
#pragma unroll
            for (int u = 0; u < 4; ++u)
                rb[0][u] = *(const float4*)(wp + (size_t)u * OUT_F);

            const float* xb = buf + (jg * JT) * KC + kq * KTC;
            for (int st = 0; st < NSTC; ++st) {
                const int nx = (st + 1 < NSTC) ? st + 1 : NSTC - 1;  // clamp
                const int nb = (st + 1) & 1, cb = st & 1;
                const float* wn = wp + (size_t)(nx * 4) * OUT_F;
#pragma unroll
                for (int u = 0; u < 4; ++u)
                    rb[nb][u] = *(const float4*)(wn + (size_t)u * OUT_F);
#pragma unroll
                for (int j = 0; j < JT; ++j) {
                    const float4 xv = *(const float4*)(xb + j * KC + st * 4);
                    fma4(acc[j], xv.x, rb[cb][0]);
                    fma4(acc[j], xv.y, rb[cb][1]);
                    fma4(acc[j], xv.z, rb[cb][2]);
                    fma4(acc[j], xv.w, rb[cb][3]);
                }
            }
        }

        // kq-reduce through LDS, then sole-owner store
        __syncthreads();
        float4* Red = (float4*)buf;     // [KQ][J][32] float4 (fits 64 KB)
#pragma unroll
        for (int j = 0; j < JT; ++j)
            Red[(kq * J + jg * JT + j) * 32 + ct] = acc[j];
        __syncthreads();

        for (int t = tid; t < J * 32; t += 256) {
            const int j = t >> 5, c = t & 31;
            if (j < nc) {
                float4 s = Red[j * 32 + c];
#pragma unroll
                for (int q = 1; q < KQ; ++q) add4(s, Red[(q * J + j) * 32 + c]);
                float* op = dst + (size_t)list[s0 + j] * OUT_F + c0 + c * 4;
                if (DELTA) {
                    *(float4*)op = s;   // raw partial into ws
                } else {
                    const float4 bv =
                        *(const float4*)(bias + (size_t)g * OUT_F + c0 + c * 4);
                    add4(s, bv);
                    *(float4*)op = s;
                }
            }
        }
        // next s0 iteration's first __syncthreads protects buf
    }
}

// 640 blocks: bid%5==0 -> base (32 heads x 4 tiles = 128 blocks, J=64 covers
// the whole head in one chunk -> W streamed exactly once, out = acc + bias);
// else -> delta (128 combos x 4 tiles = 512 blocks, raw partials to ws).
__global__ __launch_bounds__(256, 2) void lms_fused(
    const float* __restrict__ X, const int* __restrict__ head_ix,
    const int* __restrict__ split_ix, const float* __restrict__ W,
    const float* __restrict__ D, const float* __restrict__ bias,
    float* __restrict__ out, float* __restrict__ ws)
{
    __shared__ float buf[16384];        // 64 KB: Xs chunks <-> Red
    __shared__ int   list[N_SAMP];
    __shared__ int   wsum[4];

    const int bid = blockIdx.x;
    const int r5  = bid % 5;
    if (r5 == 0) {
        const int id = bid / 5;                  // 0..127
        role_pass<64, 4, 2, 256, false>(X, head_ix, split_ix,
            W, bias, out, id & 31, id >> 5, buf, list, wsum);
    } else {
        const int id = (bid / 5) * 4 + (r5 - 1); // 0..511
        role_pass<16, 2, 4, 512, true>(X, head_ix, split_ix,
            D, bias, ws, id & 127, id >> 7, buf, list, wsum);
    }
}

// out += 0.1 * ws (every ws element written: each sample's combo is non-empty
// by construction and its 4 tiles cover all 512 cols)
__global__ __launch_bounds__(256) void combine_kernel(
    float* __restrict__ out, const float* __restrict__ ws)
{
    const int i = blockIdx.x * 256 + threadIdx.x;
    float4 o = ((float4*)out)[i];
    const float4 d = ((const float4*)ws)[i];
    o.x += DELTA_SCALE * d.x; o.y += DELTA_SCALE * d.y;
    o.z += DELTA_SCALE * d.z; o.w += DELTA_SCALE * d.w;
    ((float4*)out)[i] = o;
}

extern "C" void kernel_launch(void* const* d_in, const int* in_sizes, int n_in,
                              void* d_out, int out_size, void* d_ws, size_t ws_size,
                              hipStream_t stream) {
    const float* X        = (const float*)d_in[0];
    const int*   head_ix  = (const int*)d_in[1];
    const int*   split_ix = (const int*)d_in[2];
    const float* W        = (const float*)d_in[3];
    const float* D        = (const float*)d_in[4];
    const float* bias     = (const float*)d_in[5];
    float*       out      = (float*)d_out;
    float*       ws       = (float*)d_ws;

    lms_fused<<<640, 256, 0, stream>>>(X, head_ix, split_ix, W, D, bias, out, ws);
    combine_kernel<<<(N_SAMP * OUT_F / 4) / 256, 256, 0, stream>>>(out, ws);
}

// Round 9
// 265.262 us; speedup vs baseline: 1.4613x; 1.4613x over previous
//
#include <hip/hip_runtime.h>

#define N_SAMP   1024
#define IN_F     512
#define OUT_F    512
#define N_HEADS  32
#define N_SPLITS 4
#define DELTA_SCALE 0.1f

__device__ __forceinline__ void fma4(float4& a, float x, const float4& w) {
    a.x += x * w.x; a.y += x * w.y; a.z += x * w.z; a.w += x * w.w;
}
__device__ __forceinline__ void add4(float4& a, const float4& b) {
    a.x += b.x; a.y += b.y; a.z += b.z; a.w += b.w;
}

// role_pass<J, JG, KQ, KC, DELTA>, 128-col tile.
// threads = (ct = col-quad 0..31, kq = k-split, jg = sample-group).
//   base  J=64 (one chunk covers max head -> W read ONCE), JT=16, acc=64 reg
//   delta J=16, JT=8, acc=32 reg
// R7/R8 lesson: WRITE_SIZE 210-227 MB was rb[2][4] demoted to SCRATCH --
// runtime nb/cb indexing of a register array. Fixed here with an explicit
// 2-step software pipeline over named arrays rbA/rbB (constant indices only,
// clamped-redundant tail loads). W/D stream HBM->registers; X staged in
// KC-chunks in LDS (wave-broadcast b128 reads); kq-partials reduced via
// Red aliasing buf; sole-owner stores (no atomics). DELTA writes raw
// partials to ws so base/delta run concurrently in one dispatch.
template <int J, int JG, int KQ, int KC, bool DELTA>
__device__ __forceinline__ void role_pass(
    const float* __restrict__ X, const int* __restrict__ head_ix,
    const int* __restrict__ split_ix, const float* __restrict__ Wt,
    const float* __restrict__ bias, float* __restrict__ dst,
    int g, int tileIdx, float* buf, int* list, int* wsum)
{
    constexpr int JT   = J / JG;        // samples per thread
    constexpr int KTC  = KC / KQ;       // k-rows per thread per chunk
    constexpr int NSTC = KTC / 4;       // 4-row steps per chunk (even)
    constexpr int NCH  = IN_F / KC;     // staged chunks

    const int tid  = threadIdx.x;
    const int lane = tid & 63, wave = tid >> 6;
    const int ct   = tid & 31;
    const int kq   = (tid >> 5) & (KQ - 1);
    const int jg   = tid / (32 * KQ);
    const int c0   = tileIdx * 128;

    // deterministic order-preserving compaction (all blocks of g agree)
    int run = 0;
    for (int r = 0; r < N_SAMP / 256; ++r) {
        const int i   = r * 256 + tid;
        const int key = DELTA ? head_ix[i] * N_SPLITS + split_ix[i] : head_ix[i];
        const bool hit = (key == g);
        const unsigned long long m = __ballot(hit);
        if (lane == 0) wsum[wave] = __popcll(m);
        __syncthreads();
        int base = run;
        for (int w = 0; w < 4; ++w)
            if (w < wave) base += wsum[w];
        if (hit)
            list[base + __popcll(m & ((1ULL << lane) - 1ULL))] = i;
        run += wsum[0] + wsum[1] + wsum[2] + wsum[3];
        __syncthreads();
    }
    const int total = run;
    if (total == 0) return;             // block-uniform

    const float* Wg = Wt + (size_t)g * (IN_F * OUT_F) + c0 + ct * 4;

    for (int s0 = 0; s0 < total; s0 += J) {   // expected 1 iteration
        const int nc = min(total - s0, J);

        float4 acc[JT];
#pragma unroll
        for (int j = 0; j < JT; ++j) acc[j] = make_float4(0.f, 0.f, 0.f, 0.f);

        for (int ch = 0; ch < NCH; ++ch) {
            const int kc = ch * KC;
            __syncthreads();            // buf may hold prev Red / prev chunk
            for (int i = tid; i < J * (KC / 4); i += 256) {
                const int s = i / (KC / 4), q = i % (KC / 4);
                float4 v = make_float4(0.f, 0.f, 0.f, 0.f);
                if (s < nc)
                    v = *(const float4*)(X + (size_t)list[s0 + s] * IN_F + kc + q * 4);
                *(float4*)(&buf[s * KC + q * 4]) = v;
            }
            __syncthreads();

            const float* wp = Wg + (size_t)(kc + kq * KTC) * OUT_F;
            const float* xb = buf + (jg * JT) * KC + kq * KTC;

            // explicit 2-step pipeline, constant buffer indices (NO runtime
            // indexing -> rbA/rbB stay in VGPRs)
            float4 rbA[4], rbB[4];
#pragma unroll
            for (int u = 0; u < 4; ++u)
                rbA[u] = *(const float4*)(wp + (size_t)u * OUT_F);

            for (int st = 0; st < NSTC; st += 2) {
                {   // prefetch step st+1 into rbB (always valid: NSTC even)
                    const float* wn = wp + (size_t)((st + 1) * 4) * OUT_F;
#pragma unroll
                    for (int u = 0; u < 4; ++u)
                        rbB[u] = *(const float4*)(wn + (size_t)u * OUT_F);
                }
#pragma unroll
                for (int j = 0; j < JT; ++j) {          // consume st with rbA
                    const float4 xv = *(const float4*)(xb + j * KC + st * 4);
                    fma4(acc[j], xv.x, rbA[0]);
                    fma4(acc[j], xv.y, rbA[1]);
                    fma4(acc[j], xv.z, rbA[2]);
                    fma4(acc[j], xv.w, rbA[3]);
                }
                {   // prefetch step st+2 into rbA (clamped tail: L1-hit redo)
                    const int nx = (st + 2 < NSTC) ? st + 2 : NSTC - 1;
                    const float* wn = wp + (size_t)(nx * 4) * OUT_F;
#pragma unroll
                    for (int u = 0; u < 4; ++u)
                        rbA[u] = *(const float4*)(wn + (size_t)u * OUT_F);
                }
#pragma unroll
                for (int j = 0; j < JT; ++j) {          // consume st+1 with rbB
                    const float4 xv = *(const float4*)(xb + j * KC + (st + 1) * 4);
                    fma4(acc[j], xv.x, rbB[0]);
                    fma4(acc[j], xv.y, rbB[1]);
                    fma4(acc[j], xv.z, rbB[2]);
                    fma4(acc[j], xv.w, rbB[3]);
                }
            }
        }

        // kq-reduce through LDS, then sole-owner store
        __syncthreads();
        float4* Red = (float4*)buf;     // [KQ][J][32] float4 (fits 64 KB)
#pragma unroll
        for (int j = 0; j < JT; ++j)
            Red[(kq * J + jg * JT + j) * 32 + ct] = acc[j];
        __syncthreads();

        for (int t = tid; t < J * 32; t += 256) {
            const int j = t >> 5, c = t & 31;
            if (j < nc) {
                float4 s = Red[j * 32 + c];
#pragma unroll
                for (int q = 1; q < KQ; ++q) add4(s, Red[(q * J + j) * 32 + c]);
                float* op = dst + (size_t)list[s0 + j] * OUT_F + c0 + c * 4;
                if (DELTA) {
                    *(float4*)op = s;   // raw partial into ws
                } else {
                    const float4 bv =
                        *(const float4*)(bias + (size_t)g * OUT_F + c0 + c * 4);
                    add4(s, bv);
                    *(float4*)op = s;
                }
            }
        }
        // next s0 iteration's first __syncthreads protects buf
    }
}

// 640 blocks: bid%5==0 -> base (32 heads x 4 tiles = 128 blocks, J=64 covers
// the whole head in one chunk -> W streamed exactly once, out = acc + bias);
// else -> delta (128 combos x 4 tiles = 512 blocks, raw partials to ws).
__global__ __launch_bounds__(256, 2) void lms_fused(
    const float* __restrict__ X, const int* __restrict__ head_ix,
    const int* __restrict__ split_ix, const float* __restrict__ W,
    const float* __restrict__ D, const float* __restrict__ bias,
    float* __restrict__ out, float* __restrict__ ws)
{
    __shared__ float buf[16384];        // 64 KB: Xs chunks <-> Red
    __shared__ int   list[N_SAMP];
    __shared__ int   wsum[4];

    const int bid = blockIdx.x;
    const int r5  = bid % 5;
    if (r5 == 0) {
        const int id = bid / 5;                  // 0..127
        role_pass<64, 4, 2, 256, false>(X, head_ix, split_ix,
            W, bias, out, id & 31, id >> 5, buf, list, wsum);
    } else {
        const int id = (bid / 5) * 4 + (r5 - 1); // 0..511
        role_pass<16, 2, 4, 512, true>(X, head_ix, split_ix,
            D, bias, ws, id & 127, id >> 7, buf, list, wsum);
    }
}

// out += 0.1 * ws (every ws element written: each sample's combo contains the
// sample itself -> nonempty, and its 4 tiles cover all 512 cols)
__global__ __launch_bounds__(256) void combine_kernel(
    float* __restrict__ out, const float* __restrict__ ws)
{
    const int i = blockIdx.x * 256 + threadIdx.x;
    float4 o = ((float4*)out)[i];
    const float4 d = ((const float4*)ws)[i];
    o.x += DELTA_SCALE * d.x; o.y += DELTA_SCALE * d.y;
    o.z += DELTA_SCALE * d.z; o.w += DELTA_SCALE * d.w;
    ((float4*)out)[i] = o;
}

extern "C" void kernel_launch(void* const* d_in, const int* in_sizes, int n_in,
                              void* d_out, int out_size, void* d_ws, size_t ws_size,
                              hipStream_t stream) {
    const float* X        = (const float*)d_in[0];
    const int*   head_ix  = (const int*)d_in[1];
    const int*   split_ix = (const int*)d_in[2];
    const float* W        = (const float*)d_in[3];
    const float* D        = (const float*)d_in[4];
    const float* bias     = (const float*)d_in[5];
    float*       out      = (float*)d_out;
    float*       ws       = (float*)d_ws;

    lms_fused<<<640, 256, 0, stream>>>(X, head_ix, split_ix, W, D, bias, out, ws);
    combine_kernel<<<(N_SAMP * OUT_F / 4) / 256, 256, 0, stream>>>(out, ws);
}